// Round 12
// baseline (137.977 us; speedup 1.0000x reference)
//
#include <hip/hip_runtime.h>
#include <math.h>

// ============================================================================
// MultiHeadSelfAttention: hs(2,2048,1024) fp32, W{q,k,v,o}(1024,1024) fp32.
// R12: launch-chain diet. (1) hs f32->bf16 conversion fused INTO qkv_gemm's
// A-staging (T14 split: fp32 loads issued at period start, cvt + swizzled
// ds_write after compute, one barrier) -> cvt_hs kernel and hsb round-trip
// eliminated. (2) rope + 4x weight-cvt merged into one prep kernel.
// 6 launches -> 4. attn (R11, KB=128) and out_gemm (R8) unchanged.
// ============================================================================

typedef __bf16 bf16_t;
typedef __bf16 bf16x8 __attribute__((ext_vector_type(8)));
typedef __bf16 bf16x4 __attribute__((ext_vector_type(4)));
typedef float f32x4 __attribute__((ext_vector_type(4)));
typedef float f32x16 __attribute__((ext_vector_type(16)));

#define AS1 __attribute__((address_space(1)))
#define AS3 __attribute__((address_space(3)))

#define SCALE_Q 0.18033688011112042f  // 0.125 * log2(e)

__device__ __forceinline__ void gld_lds16(const bf16_t* g, bf16_t* l) {
  __builtin_amdgcn_global_load_lds((const AS1 unsigned int*)(const void*)g,
                                   (AS3 unsigned int*)(void*)l, 16, 0, 0);
}

// ---------------- prep: 4 weight matrices -> bf16, + RoPE tables ------------
// grid (1024, 5): y<4 = weight cvt (262144 float4 each), y==4 = rope tables.
__global__ void prep_k(const float* __restrict__ a, const float* __restrict__ b,
                       const float* __restrict__ c, const float* __restrict__ d,
                       bf16_t* __restrict__ out, float* __restrict__ cost,
                       float* __restrict__ sint) {
  const int y = blockIdx.y;
  if (y < 4) {
    int i = blockIdx.x * blockDim.x + threadIdx.x;  // < 262144
    const float* src = y == 0 ? a : y == 1 ? b : y == 2 ? c : d;
    f32x4 v = ((const f32x4*)src)[i];
    bf16x4 o = {(bf16_t)v[0], (bf16_t)v[1], (bf16_t)v[2], (bf16_t)v[3]};
    ((bf16x4*)(out + (size_t)y * 1048576))[i] = o;
  } else {
    if (blockIdx.x >= 256) return;  // 65536 table entries
    int i = blockIdx.x * blockDim.x + threadIdx.x;
    int j = i & 31, s = i >> 5;
    float invf = powf(10000.0f, -(float)j * (1.0f / 32.0f));
    float ang = (float)s * invf;
    cost[i] = cosf(ang);
    sint[i] = sinf(ang);
  }
}

// ============================================================================
// GEMM core (R8-verified): 128x128 tile, BK=64, dbuf, swizzled LDS.
// key(r) = ((r&7)+(r>>3))&7 on the 16B slot index.
// ============================================================================

// stage A+B tiles via gld_lds16 (bf16 sources) — used by out_gemm.
#define GEMM_STAGE(buf, k0)                                                     \
  {                                                                             \
    _Pragma("unroll") for (int c = 0; c < 4; ++c) {                             \
      const int rg = wid * 4 + c;                                               \
      const int r = rg * 8 + sr8;                                               \
      const int key = (sr8 + rg) & 7;                                           \
      const int sc = (scol ^ key) << 3; /* element col in row */                \
      const int dst = rg * 1024 + (lane << 4);                                  \
      gld_lds16(A + (size_t)(brow + r) * 1024 + (k0) + sc,                      \
                (bf16_t*)((char*)&As[buf][0] + dst));                           \
      gld_lds16(Bt + (size_t)(bcol + r) * 1024 + (k0) + sc,                     \
                (bf16_t*)((char*)&Bs[buf][0] + dst));                           \
    }                                                                           \
  }

// B-only staging (weights, bf16) — used by qkv_gemm.
#define GEMM_STAGE_B(buf, k0)                                                   \
  {                                                                             \
    _Pragma("unroll") for (int c = 0; c < 4; ++c) {                             \
      const int rg = wid * 4 + c;                                               \
      const int key = (sr8 + rg) & 7;                                           \
      gld_lds16(Bt + (size_t)(bcol + rg * 8 + sr8) * 1024 + (k0) +              \
                    ((scol ^ key) << 3),                                        \
                (bf16_t*)((char*)&Bs[buf][0] + rg * 1024 + (lane << 4)));       \
    }                                                                           \
  }

// A fp32 loads (issue early; linear, coalesced: 8 lanes x 32B per row)
#define QKV_ALOAD(k0)                                                           \
  {                                                                             \
    _Pragma("unroll") for (int c = 0; c < 4; ++c) {                             \
      const float* srcp =                                                       \
          A + (size_t)(brow + (wid * 4 + c) * 8 + sr8) * 1024 + (k0) + scol * 8;\
      areg[c][0] = ((const f32x4*)srcp)[0];                                     \
      areg[c][1] = ((const f32x4*)srcp)[1];                                     \
    }                                                                           \
  }

// A cvt + swizzled LDS write (late; slot = scol^key matches read side)
#define QKV_AWRITE(buf)                                                         \
  {                                                                             \
    _Pragma("unroll") for (int c = 0; c < 4; ++c) {                             \
      const int rg = wid * 4 + c;                                               \
      const int key = (sr8 + rg) & 7;                                           \
      bf16x8 w;                                                                 \
      _Pragma("unroll") for (int j = 0; j < 4; ++j) {                           \
        w[j] = (bf16_t)areg[c][0][j];                                           \
        w[4 + j] = (bf16_t)areg[c][1][j];                                       \
      }                                                                         \
      *(bf16x8*)((char*)&As[buf][0] + rg * 1024 + sr8 * 128 +                   \
                 ((scol ^ key) << 4)) = w;                                      \
    }                                                                           \
  }

#define GEMM_COMPUTE(cur)                                                       \
  {                                                                             \
    _Pragma("unroll") for (int kk = 0; kk < 2; ++kk) {                          \
      bf16x8 af[4], bfr[4];                                                     \
      _Pragma("unroll") for (int mm = 0; mm < 4; ++mm) {                        \
        const int keyA = ((lr & 7) + (lr >> 3) + 2 * mm) & 7;                   \
        af[mm] = *(const bf16x8*)((const char*)&As[cur][0] +                    \
                                  (wr * 64 + mm * 16 + lr) * 128 +              \
                                  ((kk * 64 + lg * 16) ^ (keyA << 4)));         \
      }                                                                         \
      _Pragma("unroll") for (int nn = 0; nn < 4; ++nn) {                        \
        const int keyB = ((lr & 7) + (lr >> 3) + 2 * nn) & 7;                   \
        bfr[nn] = *(const bf16x8*)((const char*)&Bs[cur][0] +                   \
                                   (wc * 64 + nn * 16 + lr) * 128 +             \
                                   ((kk * 64 + lg * 16) ^ (keyB << 4)));        \
      }                                                                         \
      _Pragma("unroll") for (int mm = 0; mm < 4; ++mm)                          \
          _Pragma("unroll") for (int nn = 0; nn < 4; ++nn) acc[mm][nn] =        \
          __builtin_amdgcn_mfma_f32_16x16x32_bf16(af[mm], bfr[nn],              \
                                                  acc[mm][nn], 0, 0, 0);        \
    }                                                                           \
  }

// ---------------- fused QKV GEMM (fp32 A fused-cvt, dbuf, XCD-chunked) ------
__global__ __launch_bounds__(256) void qkv_gemm(const float* __restrict__ A,
                                                const bf16_t* __restrict__ Wq,
                                                const bf16_t* __restrict__ Wk,
                                                const bf16_t* __restrict__ Wv,
                                                bf16_t* __restrict__ Qr,
                                                bf16_t* __restrict__ Kr,
                                                bf16_t* __restrict__ Vtr,
                                                const float* __restrict__ cost,
                                                const float* __restrict__ sint) {
  __shared__ bf16_t As[2][128 * 64];
  __shared__ bf16_t Bs[2][128 * 64];
  int lid = blockIdx.y * 24 + blockIdx.x;
  lid = (lid & 7) * 96 + (lid >> 3);
  const int bx = lid % 24, by = lid / 24;
  const int which = bx >> 3;
  const int bcol = (bx & 7) * 128;
  const int brow = by * 128;
  const bf16_t* Bt = which == 0 ? Wq : which == 1 ? Wk : Wv;

  const int tid = threadIdx.x;
  const int wid = tid >> 6, lane = tid & 63;
  const int lr = lane & 15, lg = lane >> 4;
  const int wr = wid >> 1, wc = wid & 1;
  const int sr8 = lane >> 3, scol = lane & 7;

  f32x4 acc[4][4];
#pragma unroll
  for (int m = 0; m < 4; ++m)
#pragma unroll
    for (int n = 0; n < 4; ++n) acc[m][n] = (f32x4){0.f, 0.f, 0.f, 0.f};

  f32x4 areg[4][2];  // in-flight A fp32 (static indices only)

  // prologue: fill buffer 0
  QKV_ALOAD(0)
  QKV_AWRITE(0)
  GEMM_STAGE_B(0, 0)
  __syncthreads();

  for (int kt = 0; kt < 16; ++kt) {
    const int cur = kt & 1;
    if (kt < 15) {
      QKV_ALOAD((kt + 1) * 64)       // issue fp32 loads early
      GEMM_STAGE_B(cur ^ 1, (kt + 1) * 64)
    }
    GEMM_COMPUTE(cur)                // loads age under the MFMA block
    if (kt < 15) QKV_AWRITE(cur ^ 1) // cvt + swizzled ds_write, then publish
    __syncthreads();
  }

  if (which == 2) {
    // V^T epilogue, kv-permutation pre-applied (4-blocks 1<->2 per 16 group)
#pragma unroll
    for (int m = 0; m < 4; ++m)
#pragma unroll
      for (int n = 0; n < 4; ++n) {
        int row = brow + wr * 64 + m * 16 + lg * 4;
        int col = bcol + wc * 64 + n * 16 + lr;
        int b = row >> 11, s = row & 2047;
        int lgp = ((lg & 1) << 1) | (lg >> 1);
        int sp = s - lg * 4 + lgp * 4;
        bf16x4 pack = {(bf16_t)acc[m][n][0], (bf16_t)acc[m][n][1], (bf16_t)acc[m][n][2],
                       (bf16_t)acc[m][n][3]};
        *(bf16x4*)&Vtr[((size_t)(b * 1024 + col) << 11) + sp] = pack;
      }
  } else {
    bf16_t* C = which == 0 ? Qr : Kr;
    float scale = which == 0 ? SCALE_Q : 1.0f;
#pragma unroll
    for (int m = 0; m < 4; ++m)
#pragma unroll
      for (int n = 0; n < 2; ++n) {
        int row = brow + wr * 64 + m * 16 + lg * 4;
        int col = bcol + wc * 64 + n * 16 + lr;
        int j = n * 16 + lr;
#pragma unroll
        for (int r = 0; r < 4; ++r) {
          int s = (row + r) & 2047;
          float c = cost[s * 32 + j], sn = sint[s * 32 + j];
          float x0 = acc[m][n][r], x1 = acc[m][n + 2][r];
          C[(size_t)(row + r) * 1024 + col] = (bf16_t)((x0 * c - x1 * sn) * scale);
          C[(size_t)(row + r) * 1024 + col + 32] = (bf16_t)((x1 * c + x0 * sn) * scale);
        }
      }
  }
}

// ---------------- out projection GEMM (unchanged R8) ------------------------
__global__ __launch_bounds__(256) void out_gemm(const bf16_t* __restrict__ A,
                                                const bf16_t* __restrict__ Bt,
                                                float* __restrict__ C) {
  __shared__ bf16_t As[2][128 * 64];
  __shared__ bf16_t Bs[2][128 * 64];
  int lid = blockIdx.y * 8 + blockIdx.x;
  lid = (lid & 7) * 32 + (lid >> 3);
  const int bcol = (lid & 7) * 128;
  const int brow = (lid >> 3) * 128;

  const int tid = threadIdx.x;
  const int wid = tid >> 6, lane = tid & 63;
  const int lr = lane & 15, lg = lane >> 4;
  const int wr = wid >> 1, wc = wid & 1;
  const int sr8 = lane >> 3, scol = lane & 7;

  f32x4 acc[4][4];
#pragma unroll
  for (int m = 0; m < 4; ++m)
#pragma unroll
    for (int n = 0; n < 4; ++n) acc[m][n] = (f32x4){0.f, 0.f, 0.f, 0.f};

  GEMM_STAGE(0, 0)
  __syncthreads();
  for (int kt = 0; kt < 16; ++kt) {
    const int cur = kt & 1;
    if (kt < 15) GEMM_STAGE(cur ^ 1, (kt + 1) * 64)
    GEMM_COMPUTE(cur)
    __syncthreads();
  }

#pragma unroll
  for (int m = 0; m < 4; ++m)
#pragma unroll
    for (int n = 0; n < 4; ++n) {
      int row = brow + wr * 64 + m * 16 + lg * 4;
      int col = bcol + wc * 64 + n * 16 + lr;
#pragma unroll
      for (int r = 0; r < 4; ++r) C[(size_t)(row + r) * 1024 + col] = acc[m][n][r];
    }
}

// ---------------- flash attention (unchanged R11: KB=128, 2x64 sub-tiles) ---
__global__ __launch_bounds__(256, 2) void attn_k(const bf16_t* __restrict__ Q,
                                                 const bf16_t* __restrict__ K,
                                                 const bf16_t* __restrict__ Vt,
                                                 bf16_t* __restrict__ ctx) {
  const int S = 2048, HD = 1024;
  int lid = blockIdx.y * 16 + blockIdx.x;
  lid = (lid & 7) * 64 + (lid >> 3);  // XCD chunk (512 % 8 == 0)
  const int bh = lid >> 4, bx = lid & 15;
  const int b = bh >> 4, h = bh & 15;
  const int wid = threadIdx.x >> 6, lane = threadIdx.x & 63;
  const int lq = lane & 31, hi = lane >> 5;
  const int q0 = bx * 128 + wid * 32;

  const bf16_t* Qb = Q + (size_t)b * S * HD + h * 64;
  const bf16_t* Kb = K + (size_t)b * S * HD + h * 64;
  const bf16_t* Vb = Vt + (size_t)bh * 64 * S;  // [d][s-permuted]

  __shared__ bf16_t KL[2][2][64 * 64];
  __shared__ bf16_t VL[2][2][64 * 64];

  bf16x8 qf[4];
#pragma unroll
  for (int d0 = 0; d0 < 4; ++d0)
    qf[d0] = *(const bf16x8*)&Qb[(size_t)(q0 + lq) * HD + d0 * 16 + hi * 8];

  f32x16 o0 = (f32x16)0.0f, o1 = (f32x16)0.0f, osum = (f32x16)0.0f;

  bf16x8 ones;
#pragma unroll
  for (int j = 0; j < 8; ++j) ones[j] = (bf16_t)1.0f;

  const int sr = lane >> 3, sc7 = lane & 7;
  const int key0 = (sr + wid * 2) & 7, key1 = (sr + wid * 2 + 1) & 7;
  const char* Ksrc0 = (const char*)Kb + (size_t)(wid * 16 + sr) * 2048 + ((sc7 ^ key0) << 4);
  const char* Ksrc1 = (const char*)Kb + (size_t)(wid * 16 + 8 + sr) * 2048 + ((sc7 ^ key1) << 4);
  const char* Vsrc0 = (const char*)Vb + (size_t)(wid * 16 + sr) * 4096 + ((sc7 ^ key0) << 4);
  const char* Vsrc1 = (const char*)Vb + (size_t)(wid * 16 + 8 + sr) * 4096 + ((sc7 ^ key1) << 4);
  const int sdst0 = wid * 2048 + lane * 16;
  const int sdst1 = sdst0 + 1024;

#define STAGE_SUB(buf, ss, s0)                                                  \
  {                                                                             \
    gld_lds16((const bf16_t*)(Ksrc0 + (size_t)(s0) * 2048),                     \
              (bf16_t*)((char*)&KL[buf][ss][0] + sdst0));                       \
    gld_lds16((const bf16_t*)(Ksrc1 + (size_t)(s0) * 2048),                     \
              (bf16_t*)((char*)&KL[buf][ss][0] + sdst1));                       \
    gld_lds16((const bf16_t*)(Vsrc0 + (size_t)(s0) * 2),                        \
              (bf16_t*)((char*)&VL[buf][ss][0] + sdst0));                       \
    gld_lds16((const bf16_t*)(Vsrc1 + (size_t)(s0) * 2),                        \
              (bf16_t*)((char*)&VL[buf][ss][0] + sdst1));                       \
  }

  STAGE_SUB(0, 0, 0)
  STAGE_SUB(0, 1, 64)
  __syncthreads();

  const int keyLo = ((lq & 7) + (lq >> 3)) & 7;
  const int keyHi = (keyLo + 4) & 7;

#define COMPUTE_SUB(cur, ss)                                                    \
  {                                                                             \
    bf16x8 kc0[4], kc1[4], vb0[4], vb1[4];                                      \
    _Pragma("unroll") for (int d0 = 0; d0 < 4; ++d0) {                          \
      const int base = d0 * 32 + hi * 16;                                       \
      const int wlo = base ^ (keyLo << 4), whi = base ^ (keyHi << 4);           \
      kc0[d0] = *(const bf16x8*)((const char*)&KL[cur][ss][0] + lq * 128 + wlo);\
      kc1[d0] =                                                                 \
          *(const bf16x8*)((const char*)&KL[cur][ss][0] + (32 + lq) * 128 + whi);\
      vb0[d0] = *(const bf16x8*)((const char*)&VL[cur][ss][0] + lq * 128 + wlo);\
      vb1[d0] =                                                                 \
          *(const bf16x8*)((const char*)&VL[cur][ss][0] + (32 + lq) * 128 + whi);\
    }                                                                           \
    f32x16 st0 = (f32x16)0.0f, st1 = (f32x16)0.0f;                              \
    __builtin_amdgcn_s_setprio(1);                                              \
    _Pragma("unroll") for (int d0 = 0; d0 < 4; ++d0) {                          \
      st0 = __builtin_amdgcn_mfma_f32_32x32x16_bf16(kc0[d0], qf[d0], st0, 0, 0, 0); \
      st1 = __builtin_amdgcn_mfma_f32_32x32x16_bf16(kc1[d0], qf[d0], st1, 0, 0, 0); \
    }                                                                           \
    __builtin_amdgcn_s_setprio(0);                                              \
    _Pragma("unroll") for (int r = 0; r < 16; ++r) {                            \
      st0[r] = __builtin_amdgcn_exp2f(st0[r]);                                  \
      st1[r] = __builtin_amdgcn_exp2f(st1[r]);                                  \
    }                                                                           \
    bf16x8 pa[4];                                                               \
    _Pragma("unroll") for (int j = 0; j < 8; ++j) {                             \
      pa[0][j] = (bf16_t)st0[j];                                                \
      pa[1][j] = (bf16_t)st0[8 + j];                                            \
      pa[2][j] = (bf16_t)st1[j];                                                \
      pa[3][j] = (bf16_t)st1[8 + j];                                            \
    }                                                                           \
    __builtin_amdgcn_s_setprio(1);                                              \
    _Pragma("unroll") for (int ks = 0; ks < 4; ++ks) {                          \
      o0 = __builtin_amdgcn_mfma_f32_32x32x16_bf16(pa[ks], vb0[ks], o0, 0, 0, 0);   \
      o1 = __builtin_amdgcn_mfma_f32_32x32x16_bf16(pa[ks], vb1[ks], o1, 0, 0, 0);   \
      osum = __builtin_amdgcn_mfma_f32_32x32x16_bf16(pa[ks], ones, osum, 0, 0, 0);  \
    }                                                                           \
    __builtin_amdgcn_s_setprio(0);                                              \
  }

  for (int t = 0; t < 16; ++t) {
    const int cur = t & 1;
    if (t < 15) {
      STAGE_SUB(cur ^ 1, 0, (t + 1) * 128)
      STAGE_SUB(cur ^ 1, 1, (t + 1) * 128 + 64)
    }
    COMPUTE_SUB(cur, 0)
    COMPUTE_SUB(cur, 1)
    __syncthreads();
  }

  bf16_t* cb = ctx + ((size_t)b * S + q0) * HD + h * 64 + lq;
#pragma unroll
  for (int r = 0; r < 16; ++r) {
    int qr = (r & 3) + 8 * (r >> 2) + 4 * hi;
    float nf = 1.0f / osum[r];
    cb[(size_t)qr * HD] = (bf16_t)(o0[r] * nf);
    cb[(size_t)qr * HD + 32] = (bf16_t)(o1[r] * nf);
  }
#undef COMPUTE_SUB
#undef STAGE_SUB
}

// ============================================================================
extern "C" void kernel_launch(void* const* d_in, const int* in_sizes, int n_in,
                              void* d_out, int out_size, void* d_ws, size_t ws_size,
                              hipStream_t stream) {
  const float* hs = (const float*)d_in[0];
  const float* Wq = (const float*)d_in[2];
  const float* Wk = (const float*)d_in[3];
  const float* Wv = (const float*)d_in[4];
  const float* Wo = (const float*)d_in[5];
  float* out = (float*)d_out;

  const int S = 2048, Dm = 1024;
  const int M = 2 * S;

  char* p = (char*)d_ws;
  auto alloc = [&](size_t bytes) {
    char* q = p;
    p += (bytes + 255) & ~(size_t)255;
    return q;
  };
  float* cost = (float*)alloc((size_t)S * 32 * 4);
  float* sint = (float*)alloc((size_t)S * 32 * 4);
  bf16_t* Wb = (bf16_t*)alloc((size_t)4 * Dm * Dm * 2);
  bf16_t* Wqb = Wb;
  bf16_t* Wkb = Wb + (size_t)Dm * Dm;
  bf16_t* Wvb = Wb + (size_t)2 * Dm * Dm;
  bf16_t* Wob = Wb + (size_t)3 * Dm * Dm;
  bf16_t* Qr = (bf16_t*)alloc((size_t)M * Dm * 2);
  bf16_t* Kr = (bf16_t*)alloc((size_t)M * Dm * 2);
  bf16_t* Vtr = (bf16_t*)alloc((size_t)M * Dm * 2);
  bf16_t* ctx = (bf16_t*)alloc((size_t)M * Dm * 2);

  prep_k<<<dim3(1024, 5), 256, 0, stream>>>(Wq, Wk, Wv, Wo, Wb, cost, sint);

  qkv_gemm<<<dim3(24, 32), 256, 0, stream>>>(hs, Wqb, Wkb, Wvb, Qr, Kr, Vtr, cost, sint);

  attn_k<<<dim3(16, 32), 256, 0, stream>>>(Qr, Kr, Vtr, ctx);

  out_gemm<<<dim3(8, 32), 256, 0, stream>>>(ctx, Wob, out);
}

// Round 13
// 126.124 us; speedup vs baseline: 1.0940x; 1.0940x over previous
//
#include <hip/hip_runtime.h>
#include <math.h>

// ============================================================================
// MultiHeadSelfAttention: hs(2,2048,1024) fp32, W{q,k,v,o}(1024,1024) fp32.
// R13: R12's fused A-cvt REVERTED (wave-in-the-staging-path re-serialized the
// drain; gld_lds16 async path restored, A = precomputed bf16). All prep (hs
// cvt + 4x weight cvt + rope) merged into ONE kernel -> 4 launches total.
// qkv XCD mapping changed to weights-resident: each XCD owns 3 bx-columns x
// all 32 row-panels (weights 768KB L2-resident; A streams). attn = R11
// (KB=128 2-sub-tile), out_gemm = R8. absmax must stay 0.001464844.
// ============================================================================

typedef __bf16 bf16_t;
typedef __bf16 bf16x8 __attribute__((ext_vector_type(8)));
typedef __bf16 bf16x4 __attribute__((ext_vector_type(4)));
typedef float f32x4 __attribute__((ext_vector_type(4)));
typedef float f32x16 __attribute__((ext_vector_type(16)));

#define AS1 __attribute__((address_space(1)))
#define AS3 __attribute__((address_space(3)))

#define SCALE_Q 0.18033688011112042f  // 0.125 * log2(e)

__device__ __forceinline__ void gld_lds16(const bf16_t* g, bf16_t* l) {
  __builtin_amdgcn_global_load_lds((const AS1 unsigned int*)(const void*)g,
                                   (AS3 unsigned int*)(void*)l, 16, 0, 0);
}

// ---------------- prep: hs cvt + 4 weight cvts + rope, one kernel -----------
// grid 8448 x 256: [0,4096) hs (1M float4), [4096,8192) weights (1M float4),
// [8192,8448) rope tables (65536 entries).
__global__ void prep_k(const float* __restrict__ hs, const float* __restrict__ wq,
                       const float* __restrict__ wk, const float* __restrict__ wv,
                       const float* __restrict__ wo, bf16_t* __restrict__ hsb,
                       bf16_t* __restrict__ Wb, float* __restrict__ cost,
                       float* __restrict__ sint) {
  const int bid = blockIdx.x;
  if (bid < 4096) {
    int i = bid * 256 + threadIdx.x;  // < 1048576
    f32x4 v = ((const f32x4*)hs)[i];
    bf16x4 o = {(bf16_t)v[0], (bf16_t)v[1], (bf16_t)v[2], (bf16_t)v[3]};
    ((bf16x4*)hsb)[i] = o;
  } else if (bid < 8192) {
    int i = (bid - 4096) * 256 + threadIdx.x;  // < 1048576
    int w = i >> 18;                           // 262144 float4 per weight
    const float* src = w == 0 ? wq : w == 1 ? wk : w == 2 ? wv : wo;
    f32x4 v = ((const f32x4*)src)[i & 262143];
    bf16x4 o = {(bf16_t)v[0], (bf16_t)v[1], (bf16_t)v[2], (bf16_t)v[3]};
    ((bf16x4*)Wb)[i] = o;
  } else {
    int i = (bid - 8192) * 256 + threadIdx.x;  // < 65536
    int j = i & 31, s = i >> 5;
    float invf = powf(10000.0f, -(float)j * (1.0f / 32.0f));
    float ang = (float)s * invf;
    cost[i] = cosf(ang);
    sint[i] = sinf(ang);
  }
}

// ============================================================================
// GEMM core (R8-verified): 128x128 tile, BK=64, dbuf, swizzled LDS.
// key(r) = ((r&7)+(r>>3))&7 on the 16B slot index.
// ============================================================================

#define GEMM_STAGE(buf, k0)                                                     \
  {                                                                             \
    _Pragma("unroll") for (int c = 0; c < 4; ++c) {                             \
      const int rg = wid * 4 + c;                                               \
      const int r = rg * 8 + sr8;                                               \
      const int key = (sr8 + rg) & 7;                                           \
      const int sc = (scol ^ key) << 3; /* element col in row */                \
      const int dst = rg * 1024 + (lane << 4);                                  \
      gld_lds16(A + (size_t)(brow + r) * 1024 + (k0) + sc,                      \
                (bf16_t*)((char*)&As[buf][0] + dst));                           \
      gld_lds16(Bt + (size_t)(bcol + r) * 1024 + (k0) + sc,                     \
                (bf16_t*)((char*)&Bs[buf][0] + dst));                           \
    }                                                                           \
  }

#define GEMM_COMPUTE(cur)                                                       \
  {                                                                             \
    _Pragma("unroll") for (int kk = 0; kk < 2; ++kk) {                          \
      bf16x8 af[4], bfr[4];                                                     \
      _Pragma("unroll") for (int mm = 0; mm < 4; ++mm) {                        \
        const int keyA = ((lr & 7) + (lr >> 3) + 2 * mm) & 7;                   \
        af[mm] = *(const bf16x8*)((const char*)&As[cur][0] +                    \
                                  (wr * 64 + mm * 16 + lr) * 128 +              \
                                  ((kk * 64 + lg * 16) ^ (keyA << 4)));         \
      }                                                                         \
      _Pragma("unroll") for (int nn = 0; nn < 4; ++nn) {                        \
        const int keyB = ((lr & 7) + (lr >> 3) + 2 * nn) & 7;                   \
        bfr[nn] = *(const bf16x8*)((const char*)&Bs[cur][0] +                   \
                                   (wc * 64 + nn * 16 + lr) * 128 +             \
                                   ((kk * 64 + lg * 16) ^ (keyB << 4)));        \
      }                                                                         \
      _Pragma("unroll") for (int mm = 0; mm < 4; ++mm)                          \
          _Pragma("unroll") for (int nn = 0; nn < 4; ++nn) acc[mm][nn] =        \
          __builtin_amdgcn_mfma_f32_16x16x32_bf16(af[mm], bfr[nn],              \
                                                  acc[mm][nn], 0, 0, 0);        \
    }                                                                           \
  }

// ---------------- fused QKV GEMM (bf16 A, dbuf, weights-resident XCD map) ---
__global__ __launch_bounds__(256) void qkv_gemm(const bf16_t* __restrict__ A,
                                                const bf16_t* __restrict__ Wq,
                                                const bf16_t* __restrict__ Wk,
                                                const bf16_t* __restrict__ Wv,
                                                bf16_t* __restrict__ Qr,
                                                bf16_t* __restrict__ Kr,
                                                bf16_t* __restrict__ Vtr,
                                                const float* __restrict__ cost,
                                                const float* __restrict__ sint) {
  __shared__ bf16_t As[2][128 * 64];
  __shared__ bf16_t Bs[2][128 * 64];
  // weights-resident XCD map: XCD n owns bx = n*3..n*3+2, all 32 by.
  // (hardware round-robins original lid % 8 across XCDs)
  int ol = blockIdx.y * 24 + blockIdx.x;  // 0..767
  const int xcd = ol & 7, i = ol >> 3;    // i in [0,96)
  const int bx = xcd * 3 + (i >> 5);      // 0..23
  const int by = i & 31;
  const int which = bx >> 3;        // 0=Q 1=K 2=V
  const int bcol = (bx & 7) * 128;  // within 1024
  const int brow = by * 128;
  const bf16_t* Bt = which == 0 ? Wq : which == 1 ? Wk : Wv;

  const int tid = threadIdx.x;
  const int wid = tid >> 6, lane = tid & 63;
  const int lr = lane & 15, lg = lane >> 4;
  const int wr = wid >> 1, wc = wid & 1;
  const int sr8 = lane >> 3, scol = lane & 7;

  f32x4 acc[4][4];
#pragma unroll
  for (int m = 0; m < 4; ++m)
#pragma unroll
    for (int n = 0; n < 4; ++n) acc[m][n] = (f32x4){0.f, 0.f, 0.f, 0.f};

  GEMM_STAGE(0, 0)
  __syncthreads();
  for (int kt = 0; kt < 16; ++kt) {
    const int cur = kt & 1;
    if (kt < 15) GEMM_STAGE(cur ^ 1, (kt + 1) * 64)
    GEMM_COMPUTE(cur)
    __syncthreads();
  }

  if (which == 2) {
    // V^T epilogue, kv-permutation pre-applied (4-blocks 1<->2 per 16 group)
#pragma unroll
    for (int m = 0; m < 4; ++m)
#pragma unroll
      for (int n = 0; n < 4; ++n) {
        int row = brow + wr * 64 + m * 16 + lg * 4;
        int col = bcol + wc * 64 + n * 16 + lr;
        int b = row >> 11, s = row & 2047;
        int lgp = ((lg & 1) << 1) | (lg >> 1);
        int sp = s - lg * 4 + lgp * 4;
        bf16x4 pack = {(bf16_t)acc[m][n][0], (bf16_t)acc[m][n][1], (bf16_t)acc[m][n][2],
                       (bf16_t)acc[m][n][3]};
        *(bf16x4*)&Vtr[((size_t)(b * 1024 + col) << 11) + sp] = pack;
      }
  } else {
    bf16_t* C = which == 0 ? Qr : Kr;
    float scale = which == 0 ? SCALE_Q : 1.0f;
#pragma unroll
    for (int m = 0; m < 4; ++m)
#pragma unroll
      for (int n = 0; n < 2; ++n) {
        int row = brow + wr * 64 + m * 16 + lg * 4;
        int col = bcol + wc * 64 + n * 16 + lr;
        int j = n * 16 + lr;
#pragma unroll
        for (int r = 0; r < 4; ++r) {
          int s = (row + r) & 2047;
          float c = cost[s * 32 + j], sn = sint[s * 32 + j];
          float x0 = acc[m][n][r], x1 = acc[m][n + 2][r];
          C[(size_t)(row + r) * 1024 + col] = (bf16_t)((x0 * c - x1 * sn) * scale);
          C[(size_t)(row + r) * 1024 + col + 32] = (bf16_t)((x1 * c + x0 * sn) * scale);
        }
      }
  }
}

// ---------------- out projection GEMM (unchanged R8) ------------------------
__global__ __launch_bounds__(256) void out_gemm(const bf16_t* __restrict__ A,
                                                const bf16_t* __restrict__ Bt,
                                                float* __restrict__ C) {
  __shared__ bf16_t As[2][128 * 64];
  __shared__ bf16_t Bs[2][128 * 64];
  int lid = blockIdx.y * 8 + blockIdx.x;
  lid = (lid & 7) * 32 + (lid >> 3);
  const int bcol = (lid & 7) * 128;
  const int brow = (lid >> 3) * 128;

  const int tid = threadIdx.x;
  const int wid = tid >> 6, lane = tid & 63;
  const int lr = lane & 15, lg = lane >> 4;
  const int wr = wid >> 1, wc = wid & 1;
  const int sr8 = lane >> 3, scol = lane & 7;

  f32x4 acc[4][4];
#pragma unroll
  for (int m = 0; m < 4; ++m)
#pragma unroll
    for (int n = 0; n < 4; ++n) acc[m][n] = (f32x4){0.f, 0.f, 0.f, 0.f};

  GEMM_STAGE(0, 0)
  __syncthreads();
  for (int kt = 0; kt < 16; ++kt) {
    const int cur = kt & 1;
    if (kt < 15) GEMM_STAGE(cur ^ 1, (kt + 1) * 64)
    GEMM_COMPUTE(cur)
    __syncthreads();
  }

#pragma unroll
  for (int m = 0; m < 4; ++m)
#pragma unroll
    for (int n = 0; n < 4; ++n) {
      int row = brow + wr * 64 + m * 16 + lg * 4;
      int col = bcol + wc * 64 + n * 16 + lr;
#pragma unroll
      for (int r = 0; r < 4; ++r) C[(size_t)(row + r) * 1024 + col] = acc[m][n][r];
    }
}

// ---------------- flash attention (unchanged R11: KB=128, 2x64 sub-tiles) ---
__global__ __launch_bounds__(256, 2) void attn_k(const bf16_t* __restrict__ Q,
                                                 const bf16_t* __restrict__ K,
                                                 const bf16_t* __restrict__ Vt,
                                                 bf16_t* __restrict__ ctx) {
  const int S = 2048, HD = 1024;
  int lid = blockIdx.y * 16 + blockIdx.x;
  lid = (lid & 7) * 64 + (lid >> 3);  // XCD chunk (512 % 8 == 0)
  const int bh = lid >> 4, bx = lid & 15;
  const int b = bh >> 4, h = bh & 15;
  const int wid = threadIdx.x >> 6, lane = threadIdx.x & 63;
  const int lq = lane & 31, hi = lane >> 5;
  const int q0 = bx * 128 + wid * 32;

  const bf16_t* Qb = Q + (size_t)b * S * HD + h * 64;
  const bf16_t* Kb = K + (size_t)b * S * HD + h * 64;
  const bf16_t* Vb = Vt + (size_t)bh * 64 * S;  // [d][s-permuted]

  __shared__ bf16_t KL[2][2][64 * 64];
  __shared__ bf16_t VL[2][2][64 * 64];

  bf16x8 qf[4];
#pragma unroll
  for (int d0 = 0; d0 < 4; ++d0)
    qf[d0] = *(const bf16x8*)&Qb[(size_t)(q0 + lq) * HD + d0 * 16 + hi * 8];

  f32x16 o0 = (f32x16)0.0f, o1 = (f32x16)0.0f, osum = (f32x16)0.0f;

  bf16x8 ones;
#pragma unroll
  for (int j = 0; j < 8; ++j) ones[j] = (bf16_t)1.0f;

  const int sr = lane >> 3, sc7 = lane & 7;
  const int key0 = (sr + wid * 2) & 7, key1 = (sr + wid * 2 + 1) & 7;
  const char* Ksrc0 = (const char*)Kb + (size_t)(wid * 16 + sr) * 2048 + ((sc7 ^ key0) << 4);
  const char* Ksrc1 = (const char*)Kb + (size_t)(wid * 16 + 8 + sr) * 2048 + ((sc7 ^ key1) << 4);
  const char* Vsrc0 = (const char*)Vb + (size_t)(wid * 16 + sr) * 4096 + ((sc7 ^ key0) << 4);
  const char* Vsrc1 = (const char*)Vb + (size_t)(wid * 16 + 8 + sr) * 4096 + ((sc7 ^ key1) << 4);
  const int sdst0 = wid * 2048 + lane * 16;
  const int sdst1 = sdst0 + 1024;

#define STAGE_SUB(buf, ss, s0)                                                  \
  {                                                                             \
    gld_lds16((const bf16_t*)(Ksrc0 + (size_t)(s0) * 2048),                     \
              (bf16_t*)((char*)&KL[buf][ss][0] + sdst0));                       \
    gld_lds16((const bf16_t*)(Ksrc1 + (size_t)(s0) * 2048),                     \
              (bf16_t*)((char*)&KL[buf][ss][0] + sdst1));                       \
    gld_lds16((const bf16_t*)(Vsrc0 + (size_t)(s0) * 2),                        \
              (bf16_t*)((char*)&VL[buf][ss][0] + sdst0));                       \
    gld_lds16((const bf16_t*)(Vsrc1 + (size_t)(s0) * 2),                        \
              (bf16_t*)((char*)&VL[buf][ss][0] + sdst1));                       \
  }

  STAGE_SUB(0, 0, 0)
  STAGE_SUB(0, 1, 64)
  __syncthreads();

  const int keyLo = ((lq & 7) + (lq >> 3)) & 7;
  const int keyHi = (keyLo + 4) & 7;

#define COMPUTE_SUB(cur, ss)                                                    \
  {                                                                             \
    bf16x8 kc0[4], kc1[4], vb0[4], vb1[4];                                      \
    _Pragma("unroll") for (int d0 = 0; d0 < 4; ++d0) {                          \
      const int base = d0 * 32 + hi * 16;                                       \
      const int wlo = base ^ (keyLo << 4), whi = base ^ (keyHi << 4);           \
      kc0[d0] = *(const bf16x8*)((const char*)&KL[cur][ss][0] + lq * 128 + wlo);\
      kc1[d0] =                                                                 \
          *(const bf16x8*)((const char*)&KL[cur][ss][0] + (32 + lq) * 128 + whi);\
      vb0[d0] = *(const bf16x8*)((const char*)&VL[cur][ss][0] + lq * 128 + wlo);\
      vb1[d0] =                                                                 \
          *(const bf16x8*)((const char*)&VL[cur][ss][0] + (32 + lq) * 128 + whi);\
    }                                                                           \
    f32x16 st0 = (f32x16)0.0f, st1 = (f32x16)0.0f;                              \
    __builtin_amdgcn_s_setprio(1);                                              \
    _Pragma("unroll") for (int d0 = 0; d0 < 4; ++d0) {                          \
      st0 = __builtin_amdgcn_mfma_f32_32x32x16_bf16(kc0[d0], qf[d0], st0, 0, 0, 0); \
      st1 = __builtin_amdgcn_mfma_f32_32x32x16_bf16(kc1[d0], qf[d0], st1, 0, 0, 0); \
    }                                                                           \
    __builtin_amdgcn_s_setprio(0);                                              \
    _Pragma("unroll") for (int r = 0; r < 16; ++r) {                            \
      st0[r] = __builtin_amdgcn_exp2f(st0[r]);                                  \
      st1[r] = __builtin_amdgcn_exp2f(st1[r]);                                  \
    }                                                                           \
    bf16x8 pa[4];                                                               \
    _Pragma("unroll") for (int j = 0; j < 8; ++j) {                             \
      pa[0][j] = (bf16_t)st0[j];                                                \
      pa[1][j] = (bf16_t)st0[8 + j];                                            \
      pa[2][j] = (bf16_t)st1[j];                                                \
      pa[3][j] = (bf16_t)st1[8 + j];                                            \
    }                                                                           \
    __builtin_amdgcn_s_setprio(1);                                              \
    _Pragma("unroll") for (int ks = 0; ks < 4; ++ks) {                          \
      o0 = __builtin_amdgcn_mfma_f32_32x32x16_bf16(pa[ks], vb0[ks], o0, 0, 0, 0);   \
      o1 = __builtin_amdgcn_mfma_f32_32x32x16_bf16(pa[ks], vb1[ks], o1, 0, 0, 0);   \
      osum = __builtin_amdgcn_mfma_f32_32x32x16_bf16(pa[ks], ones, osum, 0, 0, 0);  \
    }                                                                           \
    __builtin_amdgcn_s_setprio(0);                                              \
  }

  for (int t = 0; t < 16; ++t) {
    const int cur = t & 1;
    if (t < 15) {
      STAGE_SUB(cur ^ 1, 0, (t + 1) * 128)
      STAGE_SUB(cur ^ 1, 1, (t + 1) * 128 + 64)
    }
    COMPUTE_SUB(cur, 0)
    COMPUTE_SUB(cur, 1)
    __syncthreads();
  }

  bf16_t* cb = ctx + ((size_t)b * S + q0) * HD + h * 64 + lq;
#pragma unroll
  for (int r = 0; r < 16; ++r) {
    int qr = (r & 3) + 8 * (r >> 2) + 4 * hi;
    float nf = 1.0f / osum[r];
    cb[(size_t)qr * HD] = (bf16_t)(o0[r] * nf);
    cb[(size_t)qr * HD + 32] = (bf16_t)(o1[r] * nf);
  }
#undef COMPUTE_SUB
#undef STAGE_SUB
}

// ============================================================================
extern "C" void kernel_launch(void* const* d_in, const int* in_sizes, int n_in,
                              void* d_out, int out_size, void* d_ws, size_t ws_size,
                              hipStream_t stream) {
  const float* hs = (const float*)d_in[0];
  const float* Wq = (const float*)d_in[2];
  const float* Wk = (const float*)d_in[3];
  const float* Wv = (const float*)d_in[4];
  const float* Wo = (const float*)d_in[5];
  float* out = (float*)d_out;

  const int S = 2048, Dm = 1024;
  const int M = 2 * S;

  char* p = (char*)d_ws;
  auto alloc = [&](size_t bytes) {
    char* q = p;
    p += (bytes + 255) & ~(size_t)255;
    return q;
  };
  float* cost = (float*)alloc((size_t)S * 32 * 4);
  float* sint = (float*)alloc((size_t)S * 32 * 4);
  bf16_t* hsb = (bf16_t*)alloc((size_t)M * Dm * 2);
  bf16_t* Wb = (bf16_t*)alloc((size_t)4 * Dm * Dm * 2);
  bf16_t* Wqb = Wb;
  bf16_t* Wkb = Wb + (size_t)Dm * Dm;
  bf16_t* Wvb = Wb + (size_t)2 * Dm * Dm;
  bf16_t* Wob = Wb + (size_t)3 * Dm * Dm;
  bf16_t* Qr = (bf16_t*)alloc((size_t)M * Dm * 2);
  bf16_t* Kr = (bf16_t*)alloc((size_t)M * Dm * 2);
  bf16_t* Vtr = (bf16_t*)alloc((size_t)M * Dm * 2);
  bf16_t* ctx = (bf16_t*)alloc((size_t)M * Dm * 2);

  prep_k<<<8448, 256, 0, stream>>>(hs, Wq, Wk, Wv, Wo, hsb, Wb, cost, sint);

  qkv_gemm<<<dim3(24, 32), 256, 0, stream>>>(hsb, Wqb, Wkb, Wvb, Qr, Kr, Vtr, cost, sint);

  attn_k<<<dim3(16, 32), 256, 0, stream>>>(Qr, Kr, Vtr, ctx);

  out_gemm<<<dim3(8, 32), 256, 0, stream>>>(ctx, Wob, out);
}

// Round 14
// 118.411 us; speedup vs baseline: 1.1652x; 1.0651x over previous
//
#include <hip/hip_runtime.h>
#include <math.h>

// ============================================================================
// MultiHeadSelfAttention: hs(2,2048,1024) fp32, W{q,k,v,o}(1024,1024) fp32.
// R14: (1) qkv XCD map reverted to R11's chunk map (measured 51.3 vs R13's
// 54.2 — weights-resident theory lost to measurement). (2) out_gemm re-tiled
// 128x64 -> 512 blocks = 2 blocks/CU (was 256 = 1/CU, no barrier overlap
// partner). Same verified swizzle/dbuf pattern; B-tile 64 rows. attn = R11,
// prep = R13. absmax must stay exactly 0.001464844.
// ============================================================================

typedef __bf16 bf16_t;
typedef __bf16 bf16x8 __attribute__((ext_vector_type(8)));
typedef __bf16 bf16x4 __attribute__((ext_vector_type(4)));
typedef float f32x4 __attribute__((ext_vector_type(4)));
typedef float f32x16 __attribute__((ext_vector_type(16)));

#define AS1 __attribute__((address_space(1)))
#define AS3 __attribute__((address_space(3)))

#define SCALE_Q 0.18033688011112042f  // 0.125 * log2(e)

__device__ __forceinline__ void gld_lds16(const bf16_t* g, bf16_t* l) {
  __builtin_amdgcn_global_load_lds((const AS1 unsigned int*)(const void*)g,
                                   (AS3 unsigned int*)(void*)l, 16, 0, 0);
}

// ---------------- prep: hs cvt + 4 weight cvts + rope, one kernel -----------
__global__ void prep_k(const float* __restrict__ hs, const float* __restrict__ wq,
                       const float* __restrict__ wk, const float* __restrict__ wv,
                       const float* __restrict__ wo, bf16_t* __restrict__ hsb,
                       bf16_t* __restrict__ Wb, float* __restrict__ cost,
                       float* __restrict__ sint) {
  const int bid = blockIdx.x;
  if (bid < 4096) {
    int i = bid * 256 + threadIdx.x;  // < 1048576
    f32x4 v = ((const f32x4*)hs)[i];
    bf16x4 o = {(bf16_t)v[0], (bf16_t)v[1], (bf16_t)v[2], (bf16_t)v[3]};
    ((bf16x4*)hsb)[i] = o;
  } else if (bid < 8192) {
    int i = (bid - 4096) * 256 + threadIdx.x;  // < 1048576
    int w = i >> 18;
    const float* src = w == 0 ? wq : w == 1 ? wk : w == 2 ? wv : wo;
    f32x4 v = ((const f32x4*)src)[i & 262143];
    bf16x4 o = {(bf16_t)v[0], (bf16_t)v[1], (bf16_t)v[2], (bf16_t)v[3]};
    ((bf16x4*)Wb)[i] = o;
  } else {
    int i = (bid - 8192) * 256 + threadIdx.x;  // < 65536
    int j = i & 31, s = i >> 5;
    float invf = powf(10000.0f, -(float)j * (1.0f / 32.0f));
    float ang = (float)s * invf;
    cost[i] = cosf(ang);
    sint[i] = sinf(ang);
  }
}

// ============================================================================
// GEMM core (R8-verified): 128x128 tile, BK=64, dbuf, swizzled LDS.
// key(r) = ((r&7)+(r>>3))&7 on the 16B slot index.
// ============================================================================

#define GEMM_STAGE(buf, k0)                                                     \
  {                                                                             \
    _Pragma("unroll") for (int c = 0; c < 4; ++c) {                             \
      const int rg = wid * 4 + c;                                               \
      const int r = rg * 8 + sr8;                                               \
      const int key = (sr8 + rg) & 7;                                           \
      const int sc = (scol ^ key) << 3; /* element col in row */                \
      const int dst = rg * 1024 + (lane << 4);                                  \
      gld_lds16(A + (size_t)(brow + r) * 1024 + (k0) + sc,                      \
                (bf16_t*)((char*)&As[buf][0] + dst));                           \
      gld_lds16(Bt + (size_t)(bcol + r) * 1024 + (k0) + sc,                     \
                (bf16_t*)((char*)&Bs[buf][0] + dst));                           \
    }                                                                           \
  }

#define GEMM_COMPUTE(cur)                                                       \
  {                                                                             \
    _Pragma("unroll") for (int kk = 0; kk < 2; ++kk) {                          \
      bf16x8 af[4], bfr[4];                                                     \
      _Pragma("unroll") for (int mm = 0; mm < 4; ++mm) {                        \
        const int keyA = ((lr & 7) + (lr >> 3) + 2 * mm) & 7;                   \
        af[mm] = *(const bf16x8*)((const char*)&As[cur][0] +                    \
                                  (wr * 64 + mm * 16 + lr) * 128 +              \
                                  ((kk * 64 + lg * 16) ^ (keyA << 4)));         \
      }                                                                         \
      _Pragma("unroll") for (int nn = 0; nn < 4; ++nn) {                        \
        const int keyB = ((lr & 7) + (lr >> 3) + 2 * nn) & 7;                   \
        bfr[nn] = *(const bf16x8*)((const char*)&Bs[cur][0] +                   \
                                   (wc * 64 + nn * 16 + lr) * 128 +             \
                                   ((kk * 64 + lg * 16) ^ (keyB << 4)));        \
      }                                                                         \
      _Pragma("unroll") for (int mm = 0; mm < 4; ++mm)                          \
          _Pragma("unroll") for (int nn = 0; nn < 4; ++nn) acc[mm][nn] =        \
          __builtin_amdgcn_mfma_f32_16x16x32_bf16(af[mm], bfr[nn],              \
                                                  acc[mm][nn], 0, 0, 0);        \
    }                                                                           \
  }

// ---------------- fused QKV GEMM (bf16 A, dbuf, R11 XCD chunk map) ----------
__global__ __launch_bounds__(256) void qkv_gemm(const bf16_t* __restrict__ A,
                                                const bf16_t* __restrict__ Wq,
                                                const bf16_t* __restrict__ Wk,
                                                const bf16_t* __restrict__ Wv,
                                                bf16_t* __restrict__ Qr,
                                                bf16_t* __restrict__ Kr,
                                                bf16_t* __restrict__ Vtr,
                                                const float* __restrict__ cost,
                                                const float* __restrict__ sint) {
  __shared__ bf16_t As[2][128 * 64];
  __shared__ bf16_t Bs[2][128 * 64];
  int lid = blockIdx.y * 24 + blockIdx.x;
  lid = (lid & 7) * 96 + (lid >> 3);  // R11 chunk map (768 % 8 == 0)
  const int bx = lid % 24, by = lid / 24;
  const int which = bx >> 3;
  const int bcol = (bx & 7) * 128;
  const int brow = by * 128;
  const bf16_t* Bt = which == 0 ? Wq : which == 1 ? Wk : Wv;

  const int tid = threadIdx.x;
  const int wid = tid >> 6, lane = tid & 63;
  const int lr = lane & 15, lg = lane >> 4;
  const int wr = wid >> 1, wc = wid & 1;
  const int sr8 = lane >> 3, scol = lane & 7;

  f32x4 acc[4][4];
#pragma unroll
  for (int m = 0; m < 4; ++m)
#pragma unroll
    for (int n = 0; n < 4; ++n) acc[m][n] = (f32x4){0.f, 0.f, 0.f, 0.f};

  GEMM_STAGE(0, 0)
  __syncthreads();
  for (int kt = 0; kt < 16; ++kt) {
    const int cur = kt & 1;
    if (kt < 15) GEMM_STAGE(cur ^ 1, (kt + 1) * 64)
    GEMM_COMPUTE(cur)
    __syncthreads();
  }

  if (which == 2) {
    // V^T epilogue, kv-permutation pre-applied (4-blocks 1<->2 per 16 group)
#pragma unroll
    for (int m = 0; m < 4; ++m)
#pragma unroll
      for (int n = 0; n < 4; ++n) {
        int row = brow + wr * 64 + m * 16 + lg * 4;
        int col = bcol + wc * 64 + n * 16 + lr;
        int b = row >> 11, s = row & 2047;
        int lgp = ((lg & 1) << 1) | (lg >> 1);
        int sp = s - lg * 4 + lgp * 4;
        bf16x4 pack = {(bf16_t)acc[m][n][0], (bf16_t)acc[m][n][1], (bf16_t)acc[m][n][2],
                       (bf16_t)acc[m][n][3]};
        *(bf16x4*)&Vtr[((size_t)(b * 1024 + col) << 11) + sp] = pack;
      }
  } else {
    bf16_t* C = which == 0 ? Qr : Kr;
    float scale = which == 0 ? SCALE_Q : 1.0f;
#pragma unroll
    for (int m = 0; m < 4; ++m)
#pragma unroll
      for (int n = 0; n < 2; ++n) {
        int row = brow + wr * 64 + m * 16 + lg * 4;
        int col = bcol + wc * 64 + n * 16 + lr;
        int j = n * 16 + lr;
#pragma unroll
        for (int r = 0; r < 4; ++r) {
          int s = (row + r) & 2047;
          float c = cost[s * 32 + j], sn = sint[s * 32 + j];
          float x0 = acc[m][n][r], x1 = acc[m][n + 2][r];
          C[(size_t)(row + r) * 1024 + col] = (bf16_t)((x0 * c - x1 * sn) * scale);
          C[(size_t)(row + r) * 1024 + col + 32] = (bf16_t)((x1 * c + x0 * sn) * scale);
        }
      }
  }
}

// ---------------- out projection GEMM: 128x64 tiles, 2 blocks/CU ------------
// A tile [128][64] staged as before; B tile 64 rows (rg = wid*2+c, c<2).
// Waves 2x2 over (128 rows x 64 cols): wr in {0,1} M-half, wc in {0,1} 32-col.
__global__ __launch_bounds__(256) void out_gemm(const bf16_t* __restrict__ A,
                                                const bf16_t* __restrict__ Bt,
                                                float* __restrict__ C) {
  __shared__ bf16_t As[2][128 * 64];  // 16 KB each buf
  __shared__ bf16_t Bs[2][64 * 64];   // 8 KB each buf
  int lid = blockIdx.y * 16 + blockIdx.x;  // 0..511
  lid = (lid & 7) * 64 + (lid >> 3);       // XCD chunk (512 % 8 == 0)
  const int bcol = (lid & 15) * 64;
  const int brow = (lid >> 4) * 128;

  const int tid = threadIdx.x;
  const int wid = tid >> 6, lane = tid & 63;
  const int lr = lane & 15, lg = lane >> 4;
  const int wr = wid >> 1, wc = wid & 1;
  const int sr8 = lane >> 3, scol = lane & 7;

  f32x4 acc[4][2];
#pragma unroll
  for (int m = 0; m < 4; ++m)
#pragma unroll
    for (int n = 0; n < 2; ++n) acc[m][n] = (f32x4){0.f, 0.f, 0.f, 0.f};

#define OG_STAGE(buf, k0)                                                       \
  {                                                                             \
    _Pragma("unroll") for (int c = 0; c < 4; ++c) {                             \
      const int rg = wid * 4 + c;                                               \
      const int key = (sr8 + rg) & 7;                                           \
      gld_lds16(A + (size_t)(brow + rg * 8 + sr8) * 1024 + (k0) +               \
                    ((scol ^ key) << 3),                                        \
                (bf16_t*)((char*)&As[buf][0] + rg * 1024 + (lane << 4)));       \
      if (c < 2) {                                                              \
        const int rgb = wid * 2 + c;                                            \
        const int keyb = (sr8 + rgb) & 7;                                       \
        gld_lds16(Bt + (size_t)(bcol + rgb * 8 + sr8) * 1024 + (k0) +           \
                      ((scol ^ keyb) << 3),                                     \
                  (bf16_t*)((char*)&Bs[buf][0] + rgb * 1024 + (lane << 4)));    \
      }                                                                         \
    }                                                                           \
  }

#define OG_COMPUTE(cur)                                                         \
  {                                                                             \
    _Pragma("unroll") for (int kk = 0; kk < 2; ++kk) {                          \
      bf16x8 af[4], bfr[2];                                                     \
      _Pragma("unroll") for (int mm = 0; mm < 4; ++mm) {                        \
        const int keyA = ((lr & 7) + (lr >> 3) + 2 * mm) & 7;                   \
        af[mm] = *(const bf16x8*)((const char*)&As[cur][0] +                    \
                                  (wr * 64 + mm * 16 + lr) * 128 +              \
                                  ((kk * 64 + lg * 16) ^ (keyA << 4)));         \
      }                                                                         \
      _Pragma("unroll") for (int nn = 0; nn < 2; ++nn) {                        \
        const int keyB = ((lr & 7) + (lr >> 3) + 4 * wc + 2 * nn) & 7;          \
        bfr[nn] = *(const bf16x8*)((const char*)&Bs[cur][0] +                   \
                                   (wc * 32 + nn * 16 + lr) * 128 +             \
                                   ((kk * 64 + lg * 16) ^ (keyB << 4)));        \
      }                                                                         \
      _Pragma("unroll") for (int mm = 0; mm < 4; ++mm)                          \
          _Pragma("unroll") for (int nn = 0; nn < 2; ++nn) acc[mm][nn] =        \
          __builtin_amdgcn_mfma_f32_16x16x32_bf16(af[mm], bfr[nn],              \
                                                  acc[mm][nn], 0, 0, 0);        \
    }                                                                           \
  }

  OG_STAGE(0, 0)
  __syncthreads();
  for (int kt = 0; kt < 16; ++kt) {
    const int cur = kt & 1;
    if (kt < 15) OG_STAGE(cur ^ 1, (kt + 1) * 64)
    OG_COMPUTE(cur)
    __syncthreads();
  }

#pragma unroll
  for (int m = 0; m < 4; ++m)
#pragma unroll
    for (int n = 0; n < 2; ++n) {
      int row = brow + wr * 64 + m * 16 + lg * 4;
      int col = bcol + wc * 32 + n * 16 + lr;
#pragma unroll
      for (int r = 0; r < 4; ++r) C[(size_t)(row + r) * 1024 + col] = acc[m][n][r];
    }
#undef OG_STAGE
#undef OG_COMPUTE
}

// ---------------- flash attention (unchanged R11: KB=128, 2x64 sub-tiles) ---
__global__ __launch_bounds__(256, 2) void attn_k(const bf16_t* __restrict__ Q,
                                                 const bf16_t* __restrict__ K,
                                                 const bf16_t* __restrict__ Vt,
                                                 bf16_t* __restrict__ ctx) {
  const int S = 2048, HD = 1024;
  int lid = blockIdx.y * 16 + blockIdx.x;
  lid = (lid & 7) * 64 + (lid >> 3);  // XCD chunk (512 % 8 == 0)
  const int bh = lid >> 4, bx = lid & 15;
  const int b = bh >> 4, h = bh & 15;
  const int wid = threadIdx.x >> 6, lane = threadIdx.x & 63;
  const int lq = lane & 31, hi = lane >> 5;
  const int q0 = bx * 128 + wid * 32;

  const bf16_t* Qb = Q + (size_t)b * S * HD + h * 64;
  const bf16_t* Kb = K + (size_t)b * S * HD + h * 64;
  const bf16_t* Vb = Vt + (size_t)bh * 64 * S;  // [d][s-permuted]

  __shared__ bf16_t KL[2][2][64 * 64];
  __shared__ bf16_t VL[2][2][64 * 64];

  bf16x8 qf[4];
#pragma unroll
  for (int d0 = 0; d0 < 4; ++d0)
    qf[d0] = *(const bf16x8*)&Qb[(size_t)(q0 + lq) * HD + d0 * 16 + hi * 8];

  f32x16 o0 = (f32x16)0.0f, o1 = (f32x16)0.0f, osum = (f32x16)0.0f;

  bf16x8 ones;
#pragma unroll
  for (int j = 0; j < 8; ++j) ones[j] = (bf16_t)1.0f;

  const int sr = lane >> 3, sc7 = lane & 7;
  const int key0 = (sr + wid * 2) & 7, key1 = (sr + wid * 2 + 1) & 7;
  const char* Ksrc0 = (const char*)Kb + (size_t)(wid * 16 + sr) * 2048 + ((sc7 ^ key0) << 4);
  const char* Ksrc1 = (const char*)Kb + (size_t)(wid * 16 + 8 + sr) * 2048 + ((sc7 ^ key1) << 4);
  const char* Vsrc0 = (const char*)Vb + (size_t)(wid * 16 + sr) * 4096 + ((sc7 ^ key0) << 4);
  const char* Vsrc1 = (const char*)Vb + (size_t)(wid * 16 + 8 + sr) * 4096 + ((sc7 ^ key1) << 4);
  const int sdst0 = wid * 2048 + lane * 16;
  const int sdst1 = sdst0 + 1024;

#define STAGE_SUB(buf, ss, s0)                                                  \
  {                                                                             \
    gld_lds16((const bf16_t*)(Ksrc0 + (size_t)(s0) * 2048),                     \
              (bf16_t*)((char*)&KL[buf][ss][0] + sdst0));                       \
    gld_lds16((const bf16_t*)(Ksrc1 + (size_t)(s0) * 2048),                     \
              (bf16_t*)((char*)&KL[buf][ss][0] + sdst1));                       \
    gld_lds16((const bf16_t*)(Vsrc0 + (size_t)(s0) * 2),                        \
              (bf16_t*)((char*)&VL[buf][ss][0] + sdst0));                       \
    gld_lds16((const bf16_t*)(Vsrc1 + (size_t)(s0) * 2),                        \
              (bf16_t*)((char*)&VL[buf][ss][0] + sdst1));                       \
  }

  STAGE_SUB(0, 0, 0)
  STAGE_SUB(0, 1, 64)
  __syncthreads();

  const int keyLo = ((lq & 7) + (lq >> 3)) & 7;
  const int keyHi = (keyLo + 4) & 7;

#define COMPUTE_SUB(cur, ss)                                                    \
  {                                                                             \
    bf16x8 kc0[4], kc1[4], vb0[4], vb1[4];                                      \
    _Pragma("unroll") for (int d0 = 0; d0 < 4; ++d0) {                          \
      const int base = d0 * 32 + hi * 16;                                       \
      const int wlo = base ^ (keyLo << 4), whi = base ^ (keyHi << 4);           \
      kc0[d0] = *(const bf16x8*)((const char*)&KL[cur][ss][0] + lq * 128 + wlo);\
      kc1[d0] =                                                                 \
          *(const bf16x8*)((const char*)&KL[cur][ss][0] + (32 + lq) * 128 + whi);\
      vb0[d0] = *(const bf16x8*)((const char*)&VL[cur][ss][0] + lq * 128 + wlo);\
      vb1[d0] =                                                                 \
          *(const bf16x8*)((const char*)&VL[cur][ss][0] + (32 + lq) * 128 + whi);\
    }                                                                           \
    f32x16 st0 = (f32x16)0.0f, st1 = (f32x16)0.0f;                              \
    __builtin_amdgcn_s_setprio(1);                                              \
    _Pragma("unroll") for (int d0 = 0; d0 < 4; ++d0) {                          \
      st0 = __builtin_amdgcn_mfma_f32_32x32x16_bf16(kc0[d0], qf[d0], st0, 0, 0, 0); \
      st1 = __builtin_amdgcn_mfma_f32_32x32x16_bf16(kc1[d0], qf[d0], st1, 0, 0, 0); \
    }                                                                           \
    __builtin_amdgcn_s_setprio(0);                                              \
    _Pragma("unroll") for (int r = 0; r < 16; ++r) {                            \
      st0[r] = __builtin_amdgcn_exp2f(st0[r]);                                  \
      st1[r] = __builtin_amdgcn_exp2f(st1[r]);                                  \
    }                                                                           \
    bf16x8 pa[4];                                                               \
    _Pragma("unroll") for (int j = 0; j < 8; ++j) {                             \
      pa[0][j] = (bf16_t)st0[j];                                                \
      pa[1][j] = (bf16_t)st0[8 + j];                                            \
      pa[2][j] = (bf16_t)st1[j];                                                \
      pa[3][j] = (bf16_t)st1[8 + j];                                            \
    }                                                                           \
    __builtin_amdgcn_s_setprio(1);                                              \
    _Pragma("unroll") for (int ks = 0; ks < 4; ++ks) {                          \
      o0 = __builtin_amdgcn_mfma_f32_32x32x16_bf16(pa[ks], vb0[ks], o0, 0, 0, 0);   \
      o1 = __builtin_amdgcn_mfma_f32_32x32x16_bf16(pa[ks], vb1[ks], o1, 0, 0, 0);   \
      osum = __builtin_amdgcn_mfma_f32_32x32x16_bf16(pa[ks], ones, osum, 0, 0, 0);  \
    }                                                                           \
    __builtin_amdgcn_s_setprio(0);                                              \
  }

  for (int t = 0; t < 16; ++t) {
    const int cur = t & 1;
    if (t < 15) {
      STAGE_SUB(cur ^ 1, 0, (t + 1) * 128)
      STAGE_SUB(cur ^ 1, 1, (t + 1) * 128 + 64)
    }
    COMPUTE_SUB(cur, 0)
    COMPUTE_SUB(cur, 1)
    __syncthreads();
  }

  bf16_t* cb = ctx + ((size_t)b * S + q0) * HD + h * 64 + lq;
#pragma unroll
  for (int r = 0; r < 16; ++r) {
    int qr = (r & 3) + 8 * (r >> 2) + 4 * hi;
    float nf = 1.0f / osum[r];
    cb[(size_t)qr * HD] = (bf16_t)(o0[r] * nf);
    cb[(size_t)qr * HD + 32] = (bf16_t)(o1[r] * nf);
  }
#undef COMPUTE_SUB
#undef STAGE_SUB
}

// ============================================================================
extern "C" void kernel_launch(void* const* d_in, const int* in_sizes, int n_in,
                              void* d_out, int out_size, void* d_ws, size_t ws_size,
                              hipStream_t stream) {
  const float* hs = (const float*)d_in[0];
  const float* Wq = (const float*)d_in[2];
  const float* Wk = (const float*)d_in[3];
  const float* Wv = (const float*)d_in[4];
  const float* Wo = (const float*)d_in[5];
  float* out = (float*)d_out;

  const int S = 2048, Dm = 1024;
  const int M = 2 * S;

  char* p = (char*)d_ws;
  auto alloc = [&](size_t bytes) {
    char* q = p;
    p += (bytes + 255) & ~(size_t)255;
    return q;
  };
  float* cost = (float*)alloc((size_t)S * 32 * 4);
  float* sint = (float*)alloc((size_t)S * 32 * 4);
  bf16_t* hsb = (bf16_t*)alloc((size_t)M * Dm * 2);
  bf16_t* Wb = (bf16_t*)alloc((size_t)4 * Dm * Dm * 2);
  bf16_t* Wqb = Wb;
  bf16_t* Wkb = Wb + (size_t)Dm * Dm;
  bf16_t* Wvb = Wb + (size_t)2 * Dm * Dm;
  bf16_t* Wob = Wb + (size_t)3 * Dm * Dm;
  bf16_t* Qr = (bf16_t*)alloc((size_t)M * Dm * 2);
  bf16_t* Kr = (bf16_t*)alloc((size_t)M * Dm * 2);
  bf16_t* Vtr = (bf16_t*)alloc((size_t)M * Dm * 2);
  bf16_t* ctx = (bf16_t*)alloc((size_t)M * Dm * 2);

  prep_k<<<8448, 256, 0, stream>>>(hs, Wq, Wk, Wv, Wo, hsb, Wb, cost, sint);

  qkv_gemm<<<dim3(24, 32), 256, 0, stream>>>(hsb, Wqb, Wkb, Wvb, Qr, Kr, Vtr, cost, sint);

  attn_k<<<dim3(16, 32), 256, 0, stream>>>(Qr, Kr, Vtr, ctx);

  out_gemm<<<dim3(16, 32), 256, 0, stream>>>(ctx, Wob, out);
}

// Round 15
// 110.568 us; speedup vs baseline: 1.2479x; 1.0709x over previous
//
#include <hip/hip_runtime.h>
#include <math.h>

// ============================================================================
// MultiHeadSelfAttention: hs(2,2048,1024) fp32, W{q,k,v,o}(1024,1024) fp32.
// R15: qkv re-tiled 128x64 (out_gemm's proven near-floor shape): grid 1536 =
// 6/CU in two exact rounds of 3 resident (48KB LDS) -> no lone-block tail.
// Waves 1x4 (32 rows x 64 cols each) keep RoPE pairs (d,d+32) wave-local
// (acc[m][n] <-> acc[m][n+2], same as verified 128-wide epilogue).
// out_gemm / attn / prep unchanged from R14. absmax must stay 0.001464844.
// ============================================================================

typedef __bf16 bf16_t;
typedef __bf16 bf16x8 __attribute__((ext_vector_type(8)));
typedef __bf16 bf16x4 __attribute__((ext_vector_type(4)));
typedef float f32x4 __attribute__((ext_vector_type(4)));
typedef float f32x16 __attribute__((ext_vector_type(16)));

#define AS1 __attribute__((address_space(1)))
#define AS3 __attribute__((address_space(3)))

#define SCALE_Q 0.18033688011112042f  // 0.125 * log2(e)

__device__ __forceinline__ void gld_lds16(const bf16_t* g, bf16_t* l) {
  __builtin_amdgcn_global_load_lds((const AS1 unsigned int*)(const void*)g,
                                   (AS3 unsigned int*)(void*)l, 16, 0, 0);
}

// ---------------- prep: hs cvt + 4 weight cvts + rope, one kernel -----------
__global__ void prep_k(const float* __restrict__ hs, const float* __restrict__ wq,
                       const float* __restrict__ wk, const float* __restrict__ wv,
                       const float* __restrict__ wo, bf16_t* __restrict__ hsb,
                       bf16_t* __restrict__ Wb, float* __restrict__ cost,
                       float* __restrict__ sint) {
  const int bid = blockIdx.x;
  if (bid < 4096) {
    int i = bid * 256 + threadIdx.x;  // < 1048576
    f32x4 v = ((const f32x4*)hs)[i];
    bf16x4 o = {(bf16_t)v[0], (bf16_t)v[1], (bf16_t)v[2], (bf16_t)v[3]};
    ((bf16x4*)hsb)[i] = o;
  } else if (bid < 8192) {
    int i = (bid - 4096) * 256 + threadIdx.x;  // < 1048576
    int w = i >> 18;
    const float* src = w == 0 ? wq : w == 1 ? wk : w == 2 ? wv : wo;
    f32x4 v = ((const f32x4*)src)[i & 262143];
    bf16x4 o = {(bf16_t)v[0], (bf16_t)v[1], (bf16_t)v[2], (bf16_t)v[3]};
    ((bf16x4*)Wb)[i] = o;
  } else {
    int i = (bid - 8192) * 256 + threadIdx.x;  // < 65536
    int j = i & 31, s = i >> 5;
    float invf = powf(10000.0f, -(float)j * (1.0f / 32.0f));
    float ang = (float)s * invf;
    cost[i] = cosf(ang);
    sint[i] = sinf(ang);
  }
}

// ============================================================================
// 128x64-tile GEMM core (verified in R14's out_gemm): BK=64, dbuf, swizzled
// LDS, key(r) = ((r&7)+(r>>3))&7 on the 16B slot index. A tile 128 rows,
// B tile 64 rows. Stage: A rg=wid*4+c (c<4), B rgb=wid*2+c (c<2).
// ============================================================================

#define T64_STAGE(buf, k0)                                                      \
  {                                                                             \
    _Pragma("unroll") for (int c = 0; c < 4; ++c) {                             \
      const int rg = wid * 4 + c;                                               \
      const int key = (sr8 + rg) & 7;                                           \
      gld_lds16(A + (size_t)(brow + rg * 8 + sr8) * 1024 + (k0) +               \
                    ((scol ^ key) << 3),                                        \
                (bf16_t*)((char*)&As[buf][0] + rg * 1024 + (lane << 4)));       \
      if (c < 2) {                                                              \
        const int rgb = wid * 2 + c;                                            \
        const int keyb = (sr8 + rgb) & 7;                                       \
        gld_lds16(Bt + (size_t)(bcol + rgb * 8 + sr8) * 1024 + (k0) +           \
                      ((scol ^ keyb) << 3),                                     \
                  (bf16_t*)((char*)&Bs[buf][0] + rgb * 1024 + (lane << 4)));    \
      }                                                                         \
    }                                                                           \
  }

// ---------------- fused QKV GEMM: 128x64 tiles, waves 1x4 -------------------
// Wave wid owns rows wid*32..wid*32+31, ALL 64 cols: acc[2][4].
// RoPE pair (d, d+32) = (n, n+2) stays wave-local. bcol is head-aligned.
__global__ __launch_bounds__(256) void qkv_gemm(const bf16_t* __restrict__ A,
                                                const bf16_t* __restrict__ Wq,
                                                const bf16_t* __restrict__ Wk,
                                                const bf16_t* __restrict__ Wv,
                                                bf16_t* __restrict__ Qr,
                                                bf16_t* __restrict__ Kr,
                                                bf16_t* __restrict__ Vtr,
                                                const float* __restrict__ cost,
                                                const float* __restrict__ sint) {
  __shared__ bf16_t As[2][128 * 64];  // 16 KB per buf
  __shared__ bf16_t Bs[2][64 * 64];   // 8 KB per buf -> 48 KB total, 3/CU
  int lid = blockIdx.y * 48 + blockIdx.x;  // 0..1535
  lid = (lid & 7) * 192 + (lid >> 3);      // XCD chunk (1536 % 8 == 0)
  const int bx = lid % 48, by = lid / 48;
  const int which = bx >> 4;        // 0=Q 1=K 2=V
  const int bcol = (bx & 15) * 64;  // 64-aligned = head-aligned
  const int brow = by * 128;
  const bf16_t* Bt = which == 0 ? Wq : which == 1 ? Wk : Wv;

  const int tid = threadIdx.x;
  const int wid = tid >> 6, lane = tid & 63;
  const int lr = lane & 15, lg = lane >> 4;
  const int sr8 = lane >> 3, scol = lane & 7;

  f32x4 acc[2][4];
#pragma unroll
  for (int m = 0; m < 2; ++m)
#pragma unroll
    for (int n = 0; n < 4; ++n) acc[m][n] = (f32x4){0.f, 0.f, 0.f, 0.f};

  T64_STAGE(0, 0)
  __syncthreads();
  for (int kt = 0; kt < 16; ++kt) {
    const int cur = kt & 1;
    if (kt < 15) T64_STAGE(cur ^ 1, (kt + 1) * 64)
#pragma unroll
    for (int kk = 0; kk < 2; ++kk) {
      bf16x8 af[2], bfr[4];
#pragma unroll
      for (int mm = 0; mm < 2; ++mm) {
        // row = wid*32 + mm*16 + lr -> key = ((lr&7)+(lr>>3)+wid*4+2*mm)&7
        const int keyA = ((lr & 7) + (lr >> 3) + wid * 4 + 2 * mm) & 7;
        af[mm] = *(const bf16x8*)((const char*)&As[cur][0] +
                                  (wid * 32 + mm * 16 + lr) * 128 +
                                  ((kk * 64 + lg * 16) ^ (keyA << 4)));
      }
#pragma unroll
      for (int nn = 0; nn < 4; ++nn) {
        const int keyB = ((lr & 7) + (lr >> 3) + 2 * nn) & 7;
        bfr[nn] = *(const bf16x8*)((const char*)&Bs[cur][0] +
                                   (nn * 16 + lr) * 128 +
                                   ((kk * 64 + lg * 16) ^ (keyB << 4)));
      }
#pragma unroll
      for (int mm = 0; mm < 2; ++mm)
#pragma unroll
        for (int nn = 0; nn < 4; ++nn)
          acc[mm][nn] = __builtin_amdgcn_mfma_f32_16x16x32_bf16(af[mm], bfr[nn],
                                                                acc[mm][nn], 0, 0, 0);
    }
    __syncthreads();
  }

  if (which == 2) {
    // V^T epilogue, kv-permutation pre-applied (4-blocks 1<->2 per 16 group)
#pragma unroll
    for (int m = 0; m < 2; ++m)
#pragma unroll
      for (int n = 0; n < 4; ++n) {
        int row = brow + wid * 32 + m * 16 + lg * 4;
        int col = bcol + n * 16 + lr;
        int b = row >> 11, s = row & 2047;
        int lgp = ((lg & 1) << 1) | (lg >> 1);
        int sp = s - lg * 4 + lgp * 4;
        bf16x4 pack = {(bf16_t)acc[m][n][0], (bf16_t)acc[m][n][1], (bf16_t)acc[m][n][2],
                       (bf16_t)acc[m][n][3]};
        *(bf16x4*)&Vtr[((size_t)(b * 1024 + col) << 11) + sp] = pack;
      }
  } else {
    bf16_t* C = which == 0 ? Qr : Kr;
    float scale = which == 0 ? SCALE_Q : 1.0f;
#pragma unroll
    for (int m = 0; m < 2; ++m)
#pragma unroll
      for (int n = 0; n < 2; ++n) {
        int row = brow + wid * 32 + m * 16 + lg * 4;
        int col = bcol + n * 16 + lr;  // d = n*16+lr < 32 (bcol head-aligned)
        int j = n * 16 + lr;
#pragma unroll
        for (int r = 0; r < 4; ++r) {
          int s = (row + r) & 2047;
          float c = cost[s * 32 + j], sn = sint[s * 32 + j];
          float x0 = acc[m][n][r], x1 = acc[m][n + 2][r];
          C[(size_t)(row + r) * 1024 + col] = (bf16_t)((x0 * c - x1 * sn) * scale);
          C[(size_t)(row + r) * 1024 + col + 32] = (bf16_t)((x1 * c + x0 * sn) * scale);
        }
      }
  }
}

// ---------------- out projection GEMM (unchanged R14: 128x64, 2/CU) ---------
__global__ __launch_bounds__(256) void out_gemm(const bf16_t* __restrict__ A,
                                                const bf16_t* __restrict__ Bt,
                                                float* __restrict__ C) {
  __shared__ bf16_t As[2][128 * 64];
  __shared__ bf16_t Bs[2][64 * 64];
  int lid = blockIdx.y * 16 + blockIdx.x;  // 0..511
  lid = (lid & 7) * 64 + (lid >> 3);       // XCD chunk (512 % 8 == 0)
  const int bcol = (lid & 15) * 64;
  const int brow = (lid >> 4) * 128;

  const int tid = threadIdx.x;
  const int wid = tid >> 6, lane = tid & 63;
  const int lr = lane & 15, lg = lane >> 4;
  const int wr = wid >> 1, wc = wid & 1;
  const int sr8 = lane >> 3, scol = lane & 7;

  f32x4 acc[4][2];
#pragma unroll
  for (int m = 0; m < 4; ++m)
#pragma unroll
    for (int n = 0; n < 2; ++n) acc[m][n] = (f32x4){0.f, 0.f, 0.f, 0.f};

  T64_STAGE(0, 0)
  __syncthreads();
  for (int kt = 0; kt < 16; ++kt) {
    const int cur = kt & 1;
    if (kt < 15) T64_STAGE(cur ^ 1, (kt + 1) * 64)
#pragma unroll
    for (int kk = 0; kk < 2; ++kk) {
      bf16x8 af[4], bfr[2];
#pragma unroll
      for (int mm = 0; mm < 4; ++mm) {
        const int keyA = ((lr & 7) + (lr >> 3) + 2 * mm) & 7;
        af[mm] = *(const bf16x8*)((const char*)&As[cur][0] +
                                  (wr * 64 + mm * 16 + lr) * 128 +
                                  ((kk * 64 + lg * 16) ^ (keyA << 4)));
      }
#pragma unroll
      for (int nn = 0; nn < 2; ++nn) {
        const int keyB = ((lr & 7) + (lr >> 3) + 4 * wc + 2 * nn) & 7;
        bfr[nn] = *(const bf16x8*)((const char*)&Bs[cur][0] +
                                   (wc * 32 + nn * 16 + lr) * 128 +
                                   ((kk * 64 + lg * 16) ^ (keyB << 4)));
      }
#pragma unroll
      for (int mm = 0; mm < 4; ++mm)
#pragma unroll
        for (int nn = 0; nn < 2; ++nn)
          acc[mm][nn] = __builtin_amdgcn_mfma_f32_16x16x32_bf16(af[mm], bfr[nn],
                                                                acc[mm][nn], 0, 0, 0);
    }
    __syncthreads();
  }

#pragma unroll
  for (int m = 0; m < 4; ++m)
#pragma unroll
    for (int n = 0; n < 2; ++n) {
      int row = brow + wr * 64 + m * 16 + lg * 4;
      int col = bcol + wc * 32 + n * 16 + lr;
#pragma unroll
      for (int r = 0; r < 4; ++r) C[(size_t)(row + r) * 1024 + col] = acc[m][n][r];
    }
}

// ---------------- flash attention (unchanged R11: KB=128, 2x64 sub-tiles) ---
__global__ __launch_bounds__(256, 2) void attn_k(const bf16_t* __restrict__ Q,
                                                 const bf16_t* __restrict__ K,
                                                 const bf16_t* __restrict__ Vt,
                                                 bf16_t* __restrict__ ctx) {
  const int S = 2048, HD = 1024;
  int lid = blockIdx.y * 16 + blockIdx.x;
  lid = (lid & 7) * 64 + (lid >> 3);  // XCD chunk (512 % 8 == 0)
  const int bh = lid >> 4, bx = lid & 15;
  const int b = bh >> 4, h = bh & 15;
  const int wid = threadIdx.x >> 6, lane = threadIdx.x & 63;
  const int lq = lane & 31, hi = lane >> 5;
  const int q0 = bx * 128 + wid * 32;

  const bf16_t* Qb = Q + (size_t)b * S * HD + h * 64;
  const bf16_t* Kb = K + (size_t)b * S * HD + h * 64;
  const bf16_t* Vb = Vt + (size_t)bh * 64 * S;  // [d][s-permuted]

  __shared__ bf16_t KL[2][2][64 * 64];
  __shared__ bf16_t VL[2][2][64 * 64];

  bf16x8 qf[4];
#pragma unroll
  for (int d0 = 0; d0 < 4; ++d0)
    qf[d0] = *(const bf16x8*)&Qb[(size_t)(q0 + lq) * HD + d0 * 16 + hi * 8];

  f32x16 o0 = (f32x16)0.0f, o1 = (f32x16)0.0f, osum = (f32x16)0.0f;

  bf16x8 ones;
#pragma unroll
  for (int j = 0; j < 8; ++j) ones[j] = (bf16_t)1.0f;

  const int sr = lane >> 3, sc7 = lane & 7;
  const int key0 = (sr + wid * 2) & 7, key1 = (sr + wid * 2 + 1) & 7;
  const char* Ksrc0 = (const char*)Kb + (size_t)(wid * 16 + sr) * 2048 + ((sc7 ^ key0) << 4);
  const char* Ksrc1 = (const char*)Kb + (size_t)(wid * 16 + 8 + sr) * 2048 + ((sc7 ^ key1) << 4);
  const char* Vsrc0 = (const char*)Vb + (size_t)(wid * 16 + sr) * 4096 + ((sc7 ^ key0) << 4);
  const char* Vsrc1 = (const char*)Vb + (size_t)(wid * 16 + 8 + sr) * 4096 + ((sc7 ^ key1) << 4);
  const int sdst0 = wid * 2048 + lane * 16;
  const int sdst1 = sdst0 + 1024;

#define STAGE_SUB(buf, ss, s0)                                                  \
  {                                                                             \
    gld_lds16((const bf16_t*)(Ksrc0 + (size_t)(s0) * 2048),                     \
              (bf16_t*)((char*)&KL[buf][ss][0] + sdst0));                       \
    gld_lds16((const bf16_t*)(Ksrc1 + (size_t)(s0) * 2048),                     \
              (bf16_t*)((char*)&KL[buf][ss][0] + sdst1));                       \
    gld_lds16((const bf16_t*)(Vsrc0 + (size_t)(s0) * 2),                        \
              (bf16_t*)((char*)&VL[buf][ss][0] + sdst0));                       \
    gld_lds16((const bf16_t*)(Vsrc1 + (size_t)(s0) * 2),                        \
              (bf16_t*)((char*)&VL[buf][ss][0] + sdst1));                       \
  }

  STAGE_SUB(0, 0, 0)
  STAGE_SUB(0, 1, 64)
  __syncthreads();

  const int keyLo = ((lq & 7) + (lq >> 3)) & 7;
  const int keyHi = (keyLo + 4) & 7;

#define COMPUTE_SUB(cur, ss)                                                    \
  {                                                                             \
    bf16x8 kc0[4], kc1[4], vb0[4], vb1[4];                                      \
    _Pragma("unroll") for (int d0 = 0; d0 < 4; ++d0) {                          \
      const int base = d0 * 32 + hi * 16;                                       \
      const int wlo = base ^ (keyLo << 4), whi = base ^ (keyHi << 4);           \
      kc0[d0] = *(const bf16x8*)((const char*)&KL[cur][ss][0] + lq * 128 + wlo);\
      kc1[d0] =                                                                 \
          *(const bf16x8*)((const char*)&KL[cur][ss][0] + (32 + lq) * 128 + whi);\
      vb0[d0] = *(const bf16x8*)((const char*)&VL[cur][ss][0] + lq * 128 + wlo);\
      vb1[d0] =                                                                 \
          *(const bf16x8*)((const char*)&VL[cur][ss][0] + (32 + lq) * 128 + whi);\
    }                                                                           \
    f32x16 st0 = (f32x16)0.0f, st1 = (f32x16)0.0f;                              \
    __builtin_amdgcn_s_setprio(1);                                              \
    _Pragma("unroll") for (int d0 = 0; d0 < 4; ++d0) {                          \
      st0 = __builtin_amdgcn_mfma_f32_32x32x16_bf16(kc0[d0], qf[d0], st0, 0, 0, 0); \
      st1 = __builtin_amdgcn_mfma_f32_32x32x16_bf16(kc1[d0], qf[d0], st1, 0, 0, 0); \
    }                                                                           \
    __builtin_amdgcn_s_setprio(0);                                              \
    _Pragma("unroll") for (int r = 0; r < 16; ++r) {                            \
      st0[r] = __builtin_amdgcn_exp2f(st0[r]);                                  \
      st1[r] = __builtin_amdgcn_exp2f(st1[r]);                                  \
    }                                                                           \
    bf16x8 pa[4];                                                               \
    _Pragma("unroll") for (int j = 0; j < 8; ++j) {                             \
      pa[0][j] = (bf16_t)st0[j];                                                \
      pa[1][j] = (bf16_t)st0[8 + j];                                            \
      pa[2][j] = (bf16_t)st1[j];                                                \
      pa[3][j] = (bf16_t)st1[8 + j];                                            \
    }                                                                           \
    __builtin_amdgcn_s_setprio(1);                                              \
    _Pragma("unroll") for (int ks = 0; ks < 4; ++ks) {                          \
      o0 = __builtin_amdgcn_mfma_f32_32x32x16_bf16(pa[ks], vb0[ks], o0, 0, 0, 0);   \
      o1 = __builtin_amdgcn_mfma_f32_32x32x16_bf16(pa[ks], vb1[ks], o1, 0, 0, 0);   \
      osum = __builtin_amdgcn_mfma_f32_32x32x16_bf16(pa[ks], ones, osum, 0, 0, 0);  \
    }                                                                           \
    __builtin_amdgcn_s_setprio(0);                                              \
  }

  for (int t = 0; t < 16; ++t) {
    const int cur = t & 1;
    if (t < 15) {
      STAGE_SUB(cur ^ 1, 0, (t + 1) * 128)
      STAGE_SUB(cur ^ 1, 1, (t + 1) * 128 + 64)
    }
    COMPUTE_SUB(cur, 0)
    COMPUTE_SUB(cur, 1)
    __syncthreads();
  }

  bf16_t* cb = ctx + ((size_t)b * S + q0) * HD + h * 64 + lq;
#pragma unroll
  for (int r = 0; r < 16; ++r) {
    int qr = (r & 3) + 8 * (r >> 2) + 4 * hi;
    float nf = 1.0f / osum[r];
    cb[(size_t)qr * HD] = (bf16_t)(o0[r] * nf);
    cb[(size_t)qr * HD + 32] = (bf16_t)(o1[r] * nf);
  }
#undef COMPUTE_SUB
#undef STAGE_SUB
}

// ============================================================================
extern "C" void kernel_launch(void* const* d_in, const int* in_sizes, int n_in,
                              void* d_out, int out_size, void* d_ws, size_t ws_size,
                              hipStream_t stream) {
  const float* hs = (const float*)d_in[0];
  const float* Wq = (const float*)d_in[2];
  const float* Wk = (const float*)d_in[3];
  const float* Wv = (const float*)d_in[4];
  const float* Wo = (const float*)d_in[5];
  float* out = (float*)d_out;

  const int S = 2048, Dm = 1024;
  const int M = 2 * S;

  char* p = (char*)d_ws;
  auto alloc = [&](size_t bytes) {
    char* q = p;
    p += (bytes + 255) & ~(size_t)255;
    return q;
  };
  float* cost = (float*)alloc((size_t)S * 32 * 4);
  float* sint = (float*)alloc((size_t)S * 32 * 4);
  bf16_t* hsb = (bf16_t*)alloc((size_t)M * Dm * 2);
  bf16_t* Wb = (bf16_t*)alloc((size_t)4 * Dm * Dm * 2);
  bf16_t* Wqb = Wb;
  bf16_t* Wkb = Wb + (size_t)Dm * Dm;
  bf16_t* Wvb = Wb + (size_t)2 * Dm * Dm;
  bf16_t* Wob = Wb + (size_t)3 * Dm * Dm;
  bf16_t* Qr = (bf16_t*)alloc((size_t)M * Dm * 2);
  bf16_t* Kr = (bf16_t*)alloc((size_t)M * Dm * 2);
  bf16_t* Vtr = (bf16_t*)alloc((size_t)M * Dm * 2);
  bf16_t* ctx = (bf16_t*)alloc((size_t)M * Dm * 2);

  prep_k<<<8448, 256, 0, stream>>>(hs, Wq, Wk, Wv, Wo, hsb, Wb, cost, sint);

  qkv_gemm<<<dim3(48, 32), 256, 0, stream>>>(hsb, Wqb, Wkb, Wvb, Qr, Kr, Vtr, cost, sint);

  attn_k<<<dim3(16, 32), 256, 0, stream>>>(Qr, Kr, Vtr, ctx);

  out_gemm<<<dim3(16, 32), 256, 0, stream>>>(ctx, Wob, out);
}